// Round 14
// baseline (168.703 us; speedup 1.0000x reference)
//
#include <hip/hip_runtime.h>

// SimpleGraphSAGE: out = mean_agg(x[src]->dst) @ W_l + b_l + x @ W_r
// N=50000, E=640000, IN=128, HID=256.
// R18: revert R17 partitioned scatter (regressed: 2x FETCH, occupancy 29%,
//      bounce unchanged; scatter floor ~42-44us stands across 6 designs).
//      prep/agg = exact R16 (fp8 gather, f32 accum). NEW: gemm_k drops LDS
//      entirely — both MFMA fragment loads are line-perfect straight from
//      global (A: 16 rows x 64B fully consumed; B: contiguous 1KB of Wimg,
//      bit-identical to the staged layout), so stage->barrier->read bought
//      nothing. Register double-buffer across the fully-unrolled kc loop
//      (rule: no runtime-indexed vector arrays), zero barriers, LDS=0.

constexpr int N_NODES = 50000;
constexpr int N_EDGES = 640000;
constexpr int GEMM_TILES = (N_NODES + 63) / 64;     // 782
constexpr int CAP = 64;                             // slots per node

constexpr int SCAT_BLOCKS  = N_EDGES / 1024;        // 625, thread handles 4 edges
constexpr int PREPX_BLOCKS = N_NODES * 32 / 256;    // 6250, thread = 4 channels
constexpr int WPREP_BLOCKS = 256;                   // 65536 weight elems

typedef __attribute__((ext_vector_type(8))) short short8;
typedef __attribute__((ext_vector_type(4))) float f32x4;
typedef __attribute__((ext_vector_type(2))) float f32x2;
typedef _Float16 half8 __attribute__((ext_vector_type(8)));

__device__ inline unsigned short f2h(float f) {
    _Float16 h = (_Float16)f;               // v_cvt_f16_f32, RNE
    return __builtin_bit_cast(unsigned short, h);
}

// ---------------------------------------------------------------------------
// prep_k (exact R16): block-range fused [edge scatter | x->fp16+fp8 | W->fp16]
// Abf layout (fp16 [N][256]): ch 0..127 = mean (written by agg), 128..255 = x.
// Xf8: [N][128] fp8 e4m3 image of x, gather source for agg.
// ---------------------------------------------------------------------------
__global__ __launch_bounds__(256) void prep_k(const float* __restrict__ x,
                                              const int* __restrict__ ei,
                                              const float* __restrict__ Wl,
                                              const float* __restrict__ Wr,
                                              unsigned int* __restrict__ Abf_u,
                                              unsigned short* __restrict__ Wimg,
                                              int* __restrict__ cnt,
                                              int* __restrict__ slots,
                                              unsigned int* __restrict__ Xf8_u) {
    int bid = blockIdx.x, tid = threadIdx.x;
    if (bid < SCAT_BLOCKS) {
        int base = bid * 1024 + tid;
#pragma unroll
        for (int k = 0; k < 4; k++) {
            int e   = base + k * 256;
            int src = ei[e];
            int dst = ei[N_EDGES + e];
            int pos = atomicAdd(&cnt[dst], 1);
            if (pos < CAP) slots[(size_t)dst * CAP + pos] = src;
        }
    } else if (bid < SCAT_BLOCKS + PREPX_BLOCKS) {
        int t = (bid - SCAT_BLOCKS) * 256 + tid;          // < N*32
        float4 v = reinterpret_cast<const float4*>(x)[t];
        unsigned int p0 = (unsigned int)f2h(v.x) | ((unsigned int)f2h(v.y) << 16);
        unsigned int p1 = (unsigned int)f2h(v.z) | ((unsigned int)f2h(v.w) << 16);
        int row = t >> 5, c = t & 31;
        reinterpret_cast<uint2*>(Abf_u)[(size_t)row * 64 + 32 + c] =
            make_uint2(p0, p1);
        // fp8 e4m3 image (4 values -> 4 bytes), HW packed convert
        int u8 = __builtin_amdgcn_cvt_pk_fp8_f32(v.x, v.y, 0, false);
        u8     = __builtin_amdgcn_cvt_pk_fp8_f32(v.z, v.w, u8, true);
        Xf8_u[t] = (unsigned int)u8;
    } else {
        int t = (bid - SCAT_BLOCKS - PREPX_BLOCKS) * 256 + tid;  // < 65536
        int k = t >> 8, n = t & 255;
        float v = (k < 128) ? Wl[k * 256 + n] : Wr[(k - 128) * 256 + n];
        Wimg[(size_t)(k >> 5) * 8192 + n * 32 + (k & 31)] = f2h(v);
    }
}

// ---------------------------------------------------------------------------
// agg_k (exact R16): 8 nodes per wave, 8 lanes per node (sub owns 16B =
// 16 fp8 ch of the 128B row). Coalesced slot-batch load + shfl(.,J,8)
// broadcast; 8 gather chains in flight; f32 accumulate; mean -> fp16 Abf.
// ---------------------------------------------------------------------------
__global__ __launch_bounds__(256) void agg_k(const int* __restrict__ cnt,
                                             const int* __restrict__ slots,
                                             const unsigned int* __restrict__ Xf8_u,
                                             unsigned int* __restrict__ Abf_u) {
    int wave = (blockIdx.x * 256 + threadIdx.x) >> 6;  // 0..6251 (guarded)
    int lane = threadIdx.x & 63;
    int g    = lane >> 3;
    int sub  = lane & 7;
    int node = wave * 8 + g;
    if (node >= N_NODES) return;
    int dc   = cnt[node];
    int deg  = (dc > CAP) ? CAP : dc;
    const int* sl = slots + (size_t)node * CAP;
    const uint4* X8 = reinterpret_cast<const uint4*>(Xf8_u);  // row = 8 uint4

    f32x2 a0 = {0.f, 0.f}, a1 = {0.f, 0.f}, a2 = {0.f, 0.f}, a3 = {0.f, 0.f};
    f32x2 a4 = {0.f, 0.f}, a5 = {0.f, 0.f}, a6 = {0.f, 0.f}, a7 = {0.f, 0.f};

#define LOADV(vj, J)                                                    \
    uint4 vj = make_uint4(0, 0, 0, 0);                                  \
    {                                                                   \
        int sj = __shfl(slv, (J), 8);                                   \
        if (base + (J) < deg)                                           \
            vj = X8[(size_t)sj * 8 + sub];                              \
    }
#define ACCV(vj)                                                              \
    {                                                                         \
        a0 += __builtin_amdgcn_cvt_pk_f32_fp8(vj.x, false);                   \
        a1 += __builtin_amdgcn_cvt_pk_f32_fp8(vj.x, true);                    \
        a2 += __builtin_amdgcn_cvt_pk_f32_fp8(vj.y, false);                   \
        a3 += __builtin_amdgcn_cvt_pk_f32_fp8(vj.y, true);                    \
        a4 += __builtin_amdgcn_cvt_pk_f32_fp8(vj.z, false);                   \
        a5 += __builtin_amdgcn_cvt_pk_f32_fp8(vj.z, true);                    \
        a6 += __builtin_amdgcn_cvt_pk_f32_fp8(vj.w, false);                   \
        a7 += __builtin_amdgcn_cvt_pk_f32_fp8(vj.w, true);                    \
    }

    for (int base = 0; base < deg; base += 8) {
        int slv = sl[base + sub];   // 8 lanes cover the batch (32B line)
        LOADV(v0, 0) LOADV(v1, 1) LOADV(v2, 2) LOADV(v3, 3)
        LOADV(v4, 4) LOADV(v5, 5) LOADV(v6, 6) LOADV(v7, 7)
        ACCV(v0) ACCV(v1) ACCV(v2) ACCV(v3)
        ACCV(v4) ACCV(v5) ACCV(v6) ACCV(v7)
    }
#undef LOADV
#undef ACCV

    float inv = (dc > 0) ? 1.0f / (float)dc : 0.0f;
    uint4 o0, o1;
    o0.x = (unsigned int)f2h(a0.x * inv) | ((unsigned int)f2h(a0.y * inv) << 16);
    o0.y = (unsigned int)f2h(a1.x * inv) | ((unsigned int)f2h(a1.y * inv) << 16);
    o0.z = (unsigned int)f2h(a2.x * inv) | ((unsigned int)f2h(a2.y * inv) << 16);
    o0.w = (unsigned int)f2h(a3.x * inv) | ((unsigned int)f2h(a3.y * inv) << 16);
    o1.x = (unsigned int)f2h(a4.x * inv) | ((unsigned int)f2h(a4.y * inv) << 16);
    o1.y = (unsigned int)f2h(a5.x * inv) | ((unsigned int)f2h(a5.y * inv) << 16);
    o1.z = (unsigned int)f2h(a6.x * inv) | ((unsigned int)f2h(a6.y * inv) << 16);
    o1.w = (unsigned int)f2h(a7.x * inv) | ((unsigned int)f2h(a7.y * inv) << 16);
    uint4* A4 = reinterpret_cast<uint4*>(Abf_u);   // row = 32 uint4 (512B)
    A4[(size_t)node * 32 + sub * 2]     = o0;      // ch sub*16 .. sub*16+7
    A4[(size_t)node * 32 + sub * 2 + 1] = o1;      // ch sub*16+8 .. sub*16+15
}

// ---------------------------------------------------------------------------
// gemm_k (R18): out[N][256] = Abf[N][256] @ Wcat[256][256] + bl, fp16 MFMA.
// NO LDS, NO barriers. 256 threads = 4 waves, wave w owns cols w*64..w*64+63
// of a 64-row tile. Fragments loaded straight from global (A: 16 rows x 64B,
// each line fully consumed; B: contiguous 1KB of Wimg per (ct)) — layouts
// bit-identical to the previously staged reads. Register double-buffer
// across the fully-unrolled kc loop (compile-time indices only).
// ---------------------------------------------------------------------------
__global__ __launch_bounds__(256) void gemm_k(const unsigned short* __restrict__ Abf,
                                              const unsigned short* __restrict__ Wimg,
                                              const float* __restrict__ bl,
                                              float* __restrict__ out) {
    int tid  = threadIdx.x;
    int w    = tid >> 6;        // 0..3  col-quarter
    int lane = tid & 63;
    int m15  = lane & 15;
    int quad = lane >> 4;
    int bm   = blockIdx.x * 64;

    f32x4 zero4 = {0.f, 0.f, 0.f, 0.f};
    f32x4 acc[4][4];
#pragma unroll
    for (int rt = 0; rt < 4; rt++)
#pragma unroll
        for (int ct = 0; ct < 4; ct++) acc[rt][ct] = zero4;

    // per-lane base addresses (in halves)
    // A frag (rt,kc): Abf[(bm + rt*16 + m15)*256 + kc*32 + quad*8]
    // B frag (ct,kc): Wimg[kc*8192 + (w*64 + ct*16 + m15)*32 + quad*8]
    const unsigned short* Abase = Abf + ((size_t)(bm + m15) * 256 + quad * 8);
    const unsigned short* Bbase =
        Wimg + ((size_t)(w * 64 + m15) * 32 + quad * 8);

    half8 Af0[4], Bf0[4], Af1[4], Bf1[4];
#pragma unroll
    for (int rt = 0; rt < 4; rt++)
        Af0[rt] = *reinterpret_cast<const half8*>(Abase + rt * 4096);
#pragma unroll
    for (int ct = 0; ct < 4; ct++)
        Bf0[ct] = *reinterpret_cast<const half8*>(Bbase + ct * 512);

#pragma unroll
    for (int kc = 0; kc < 8; kc++) {
        if (kc & 1) {
            if (kc < 7) {
#pragma unroll
                for (int rt = 0; rt < 4; rt++)
                    Af0[rt] = *reinterpret_cast<const half8*>(
                        Abase + (kc + 1) * 32 + rt * 4096);
#pragma unroll
                for (int ct = 0; ct < 4; ct++)
                    Bf0[ct] = *reinterpret_cast<const half8*>(
                        Bbase + (size_t)(kc + 1) * 8192 + ct * 512);
            }
#pragma unroll
            for (int rt = 0; rt < 4; rt++)
#pragma unroll
                for (int ct = 0; ct < 4; ct++)
                    acc[rt][ct] = __builtin_amdgcn_mfma_f32_16x16x32_f16(
                        Af1[rt], Bf1[ct], acc[rt][ct], 0, 0, 0);
        } else {
#pragma unroll
            for (int rt = 0; rt < 4; rt++)
                Af1[rt] = *reinterpret_cast<const half8*>(
                    Abase + (kc + 1) * 32 + rt * 4096);
#pragma unroll
            for (int ct = 0; ct < 4; ct++)
                Bf1[ct] = *reinterpret_cast<const half8*>(
                    Bbase + (size_t)(kc + 1) * 8192 + ct * 512);
#pragma unroll
            for (int rt = 0; rt < 4; rt++)
#pragma unroll
                for (int ct = 0; ct < 4; ct++)
                    acc[rt][ct] = __builtin_amdgcn_mfma_f32_16x16x32_f16(
                        Af0[rt], Bf0[ct], acc[rt][ct], 0, 0, 0);
        }
    }

    float bias[4];
#pragma unroll
    for (int ct = 0; ct < 4; ct++) bias[ct] = bl[w * 64 + ct * 16 + m15];
#pragma unroll
    for (int rt = 0; rt < 4; rt++) {
        int rb = bm + rt * 16 + quad * 4;
#pragma unroll
        for (int r = 0; r < 4; r++) {
            int row = rb + r;
            if (row < N_NODES) {
#pragma unroll
                for (int ct = 0; ct < 4; ct++)
                    out[(size_t)row * 256 + w * 64 + ct * 16 + m15] =
                        acc[rt][ct][r] + bias[ct];
            }
        }
    }
}

extern "C" void kernel_launch(void* const* d_in, const int* in_sizes, int n_in,
                              void* d_out, int out_size, void* d_ws, size_t ws_size,
                              hipStream_t stream) {
    const float* x  = (const float*)d_in[0];
    const int*   ei = (const int*)d_in[1];   // [2, E] int32
    const float* Wl = (const float*)d_in[2];
    const float* bl = (const float*)d_in[3];
    const float* Wr = (const float*)d_in[4];
    float* out = (float*)d_out;

    // ws layout
    unsigned short* Abf  = (unsigned short*)d_ws;              // N*256 fp16
    unsigned short* Wimg = Abf + (size_t)N_NODES * 256;        // 65536 fp16
    int* cnt   = (int*)(Wimg + 65536);                         // N
    int* slots = cnt + N_NODES;                                // N*CAP
    unsigned int* Xf8 = (unsigned int*)(slots + (size_t)N_NODES * CAP);  // N*32 u32

    hipMemsetAsync(cnt, 0, N_NODES * sizeof(int), stream);

    prep_k<<<SCAT_BLOCKS + PREPX_BLOCKS + WPREP_BLOCKS, 256, 0, stream>>>(
        x, ei, Wl, Wr, (unsigned int*)Abf, Wimg, cnt, slots, Xf8);
    agg_k<<<(N_NODES / 8 * 64 + 255) / 256, 256, 0, stream>>>(
        cnt, slots, Xf8, (unsigned int*)Abf);
    gemm_k<<<GEMM_TILES, 256, 0, stream>>>(Abf, Wimg, bl, out);
}

// Round 15
// 164.223 us; speedup vs baseline: 1.0273x; 1.0273x over previous
//
#include <hip/hip_runtime.h>

// SimpleGraphSAGE: out = mean_agg(x[src]->dst) @ W_l + b_l + x @ W_r
// N=50000, E=640000, IN=128, HID=256.
// R19: revert R18's LDS-free gemm (regressed +13.4us: without staging all
//      4 waves re-load identical A lines; sharing > barrier cost).
//      prep/agg = exact R16 (fp8 gather, f32 accum; best = 155.3us).
//      NEW (single change): gemm BM 128->224, 512 thr, 8 waves 2Mx4N
//      (wave = 112x64, acc 7x4). Blocks 391->224 <= 256 CUs: kills the
//      2-blocks-on-half-the-CUs makespan stretch (1.31x -> 1.0) and cuts
//      per-CU row work 256->224.

constexpr int N_NODES = 50000;
constexpr int N_EDGES = 640000;
constexpr int BM = 224;
constexpr int GEMM_TILES = (N_NODES + BM - 1) / BM;  // 224
constexpr int CAP = 64;                              // slots per node

constexpr int SCAT_BLOCKS  = N_EDGES / 1024;        // 625, thread handles 4 edges
constexpr int PREPX_BLOCKS = N_NODES * 32 / 256;    // 6250, thread = 4 channels
constexpr int WPREP_BLOCKS = 256;                   // 65536 weight elems

typedef __attribute__((ext_vector_type(8))) short short8;
typedef __attribute__((ext_vector_type(4))) float f32x4;
typedef __attribute__((ext_vector_type(2))) float f32x2;
typedef _Float16 half8 __attribute__((ext_vector_type(8)));

__device__ inline unsigned short f2h(float f) {
    _Float16 h = (_Float16)f;               // v_cvt_f16_f32, RNE
    return __builtin_bit_cast(unsigned short, h);
}

// ---------------------------------------------------------------------------
// prep_k (exact R16): block-range fused [edge scatter | x->fp16+fp8 | W->fp16]
// Abf layout (fp16 [N][256]): ch 0..127 = mean (written by agg), 128..255 = x.
// Xf8: [N][128] fp8 e4m3 image of x, gather source for agg.
// ---------------------------------------------------------------------------
__global__ __launch_bounds__(256) void prep_k(const float* __restrict__ x,
                                              const int* __restrict__ ei,
                                              const float* __restrict__ Wl,
                                              const float* __restrict__ Wr,
                                              unsigned int* __restrict__ Abf_u,
                                              unsigned short* __restrict__ Wimg,
                                              int* __restrict__ cnt,
                                              int* __restrict__ slots,
                                              unsigned int* __restrict__ Xf8_u) {
    int bid = blockIdx.x, tid = threadIdx.x;
    if (bid < SCAT_BLOCKS) {
        int base = bid * 1024 + tid;
#pragma unroll
        for (int k = 0; k < 4; k++) {
            int e   = base + k * 256;
            int src = ei[e];
            int dst = ei[N_EDGES + e];
            int pos = atomicAdd(&cnt[dst], 1);
            if (pos < CAP) slots[(size_t)dst * CAP + pos] = src;
        }
    } else if (bid < SCAT_BLOCKS + PREPX_BLOCKS) {
        int t = (bid - SCAT_BLOCKS) * 256 + tid;          // < N*32
        float4 v = reinterpret_cast<const float4*>(x)[t];
        unsigned int p0 = (unsigned int)f2h(v.x) | ((unsigned int)f2h(v.y) << 16);
        unsigned int p1 = (unsigned int)f2h(v.z) | ((unsigned int)f2h(v.w) << 16);
        int row = t >> 5, c = t & 31;
        reinterpret_cast<uint2*>(Abf_u)[(size_t)row * 64 + 32 + c] =
            make_uint2(p0, p1);
        // fp8 e4m3 image (4 values -> 4 bytes), HW packed convert
        int u8 = __builtin_amdgcn_cvt_pk_fp8_f32(v.x, v.y, 0, false);
        u8     = __builtin_amdgcn_cvt_pk_fp8_f32(v.z, v.w, u8, true);
        Xf8_u[t] = (unsigned int)u8;
    } else {
        int t = (bid - SCAT_BLOCKS - PREPX_BLOCKS) * 256 + tid;  // < 65536
        int k = t >> 8, n = t & 255;
        float v = (k < 128) ? Wl[k * 256 + n] : Wr[(k - 128) * 256 + n];
        Wimg[(size_t)(k >> 5) * 8192 + n * 32 + (k & 31)] = f2h(v);
    }
}

// ---------------------------------------------------------------------------
// agg_k (exact R16): 8 nodes per wave, 8 lanes per node (sub owns 16B =
// 16 fp8 ch of the 128B row). Coalesced slot-batch load + shfl(.,J,8)
// broadcast; 8 gather chains in flight; f32 accumulate; mean -> fp16 Abf.
// ---------------------------------------------------------------------------
__global__ __launch_bounds__(256) void agg_k(const int* __restrict__ cnt,
                                             const int* __restrict__ slots,
                                             const unsigned int* __restrict__ Xf8_u,
                                             unsigned int* __restrict__ Abf_u) {
    int wave = (blockIdx.x * 256 + threadIdx.x) >> 6;  // 0..6251 (guarded)
    int lane = threadIdx.x & 63;
    int g    = lane >> 3;
    int sub  = lane & 7;
    int node = wave * 8 + g;
    if (node >= N_NODES) return;
    int dc   = cnt[node];
    int deg  = (dc > CAP) ? CAP : dc;
    const int* sl = slots + (size_t)node * CAP;
    const uint4* X8 = reinterpret_cast<const uint4*>(Xf8_u);  // row = 8 uint4

    f32x2 a0 = {0.f, 0.f}, a1 = {0.f, 0.f}, a2 = {0.f, 0.f}, a3 = {0.f, 0.f};
    f32x2 a4 = {0.f, 0.f}, a5 = {0.f, 0.f}, a6 = {0.f, 0.f}, a7 = {0.f, 0.f};

#define LOADV(vj, J)                                                    \
    uint4 vj = make_uint4(0, 0, 0, 0);                                  \
    {                                                                   \
        int sj = __shfl(slv, (J), 8);                                   \
        if (base + (J) < deg)                                           \
            vj = X8[(size_t)sj * 8 + sub];                              \
    }
#define ACCV(vj)                                                              \
    {                                                                         \
        a0 += __builtin_amdgcn_cvt_pk_f32_fp8(vj.x, false);                   \
        a1 += __builtin_amdgcn_cvt_pk_f32_fp8(vj.x, true);                    \
        a2 += __builtin_amdgcn_cvt_pk_f32_fp8(vj.y, false);                   \
        a3 += __builtin_amdgcn_cvt_pk_f32_fp8(vj.y, true);                    \
        a4 += __builtin_amdgcn_cvt_pk_f32_fp8(vj.z, false);                   \
        a5 += __builtin_amdgcn_cvt_pk_f32_fp8(vj.z, true);                    \
        a6 += __builtin_amdgcn_cvt_pk_f32_fp8(vj.w, false);                   \
        a7 += __builtin_amdgcn_cvt_pk_f32_fp8(vj.w, true);                    \
    }

    for (int base = 0; base < deg; base += 8) {
        int slv = sl[base + sub];   // 8 lanes cover the batch (32B line)
        LOADV(v0, 0) LOADV(v1, 1) LOADV(v2, 2) LOADV(v3, 3)
        LOADV(v4, 4) LOADV(v5, 5) LOADV(v6, 6) LOADV(v7, 7)
        ACCV(v0) ACCV(v1) ACCV(v2) ACCV(v3)
        ACCV(v4) ACCV(v5) ACCV(v6) ACCV(v7)
    }
#undef LOADV
#undef ACCV

    float inv = (dc > 0) ? 1.0f / (float)dc : 0.0f;
    uint4 o0, o1;
    o0.x = (unsigned int)f2h(a0.x * inv) | ((unsigned int)f2h(a0.y * inv) << 16);
    o0.y = (unsigned int)f2h(a1.x * inv) | ((unsigned int)f2h(a1.y * inv) << 16);
    o0.z = (unsigned int)f2h(a2.x * inv) | ((unsigned int)f2h(a2.y * inv) << 16);
    o0.w = (unsigned int)f2h(a3.x * inv) | ((unsigned int)f2h(a3.y * inv) << 16);
    o1.x = (unsigned int)f2h(a4.x * inv) | ((unsigned int)f2h(a4.y * inv) << 16);
    o1.y = (unsigned int)f2h(a5.x * inv) | ((unsigned int)f2h(a5.y * inv) << 16);
    o1.z = (unsigned int)f2h(a6.x * inv) | ((unsigned int)f2h(a6.y * inv) << 16);
    o1.w = (unsigned int)f2h(a7.x * inv) | ((unsigned int)f2h(a7.y * inv) << 16);
    uint4* A4 = reinterpret_cast<uint4*>(Abf_u);   // row = 32 uint4 (512B)
    A4[(size_t)node * 32 + sub * 2]     = o0;      // ch sub*16 .. sub*16+7
    A4[(size_t)node * 32 + sub * 2 + 1] = o1;      // ch sub*16+8 .. sub*16+15
}

// ---------------------------------------------------------------------------
// gemm_k (R19): out[N][256] = Abf[N][256] @ Wcat[256][256] + bl, fp16 MFMA.
// BM=224, 512 threads = 8 waves (2 row-halves x 4 col-quarters); wave tile
// 112x64 = 7rt x 4ct of 16x16x32. 224 blocks <= 256 CUs: no CU runs 2.
// Verified 2-barrier kc loop + LDS staging (sharing across waves).
// ---------------------------------------------------------------------------
__global__ __launch_bounds__(512) void gemm_k(const unsigned short* __restrict__ Abf,
                                              const unsigned short* __restrict__ Wimg,
                                              const float* __restrict__ bl,
                                              float* __restrict__ out) {
    __shared__ unsigned short As[BM * 40];    // rows padded to 40 elems (80B)
    __shared__ unsigned short Bs[256 * 40];

    int tid  = threadIdx.x;
    int w8   = tid >> 6;        // 0..7
    int wm   = w8 >> 2;         // 0..1  row-half (112 rows each)
    int wn   = w8 & 3;          // 0..3  col-quarter
    int lane = tid & 63;
    int m15  = lane & 15;
    int quad = lane >> 4;
    int bm   = blockIdx.x * BM;

    f32x4 zero4 = {0.f, 0.f, 0.f, 0.f};
    f32x4 acc[7][4];
#pragma unroll
    for (int rt = 0; rt < 7; rt++)
#pragma unroll
        for (int ct = 0; ct < 4; ct++) acc[rt][ct] = zero4;

    for (int kc = 0; kc < 8; kc++) {
        // stage A: 224 rows x 32 halves = 896 16B chunks
        for (int c = tid; c < 896; c += 512) {
            int row = c >> 2, q = c & 3;
            int grow = bm + row;
            short8 v = {0, 0, 0, 0, 0, 0, 0, 0};
            if (grow < N_NODES)
                v = *reinterpret_cast<const short8*>(
                        Abf + (size_t)grow * 256 + kc * 32 + q * 8);
            *reinterpret_cast<short8*>(As + row * 40 + q * 8) = v;
        }
        // stage B: 256 n-rows x 32 halves = 1024 16B chunks
        for (int c = tid; c < 1024; c += 512) {
            int n = c >> 2, q = c & 3;
            short8 v = *reinterpret_cast<const short8*>(
                           Wimg + (size_t)kc * 8192 + n * 32 + q * 8);
            *reinterpret_cast<short8*>(Bs + n * 40 + q * 8) = v;
        }
        __syncthreads();

        half8 Bf[4];
#pragma unroll
        for (int ct = 0; ct < 4; ct++)
            Bf[ct] = *reinterpret_cast<const half8*>(
                         Bs + (wn * 64 + ct * 16 + m15) * 40 + quad * 8);
#pragma unroll
        for (int rt = 0; rt < 7; rt++) {
            half8 Af = *reinterpret_cast<const half8*>(
                           As + (wm * 112 + rt * 16 + m15) * 40 + quad * 8);
#pragma unroll
            for (int ct = 0; ct < 4; ct++)
                acc[rt][ct] = __builtin_amdgcn_mfma_f32_16x16x32_f16(
                    Af, Bf[ct], acc[rt][ct], 0, 0, 0);
        }
        __syncthreads();
    }

    float bias[4];
#pragma unroll
    for (int ct = 0; ct < 4; ct++) bias[ct] = bl[wn * 64 + ct * 16 + m15];
#pragma unroll
    for (int rt = 0; rt < 7; rt++) {
        int rb = bm + wm * 112 + rt * 16 + quad * 4;
#pragma unroll
        for (int r = 0; r < 4; r++) {
            int row = rb + r;
            if (row < N_NODES) {
#pragma unroll
                for (int ct = 0; ct < 4; ct++)
                    out[(size_t)row * 256 + wn * 64 + ct * 16 + m15] =
                        acc[rt][ct][r] + bias[ct];
            }
        }
    }
}

extern "C" void kernel_launch(void* const* d_in, const int* in_sizes, int n_in,
                              void* d_out, int out_size, void* d_ws, size_t ws_size,
                              hipStream_t stream) {
    const float* x  = (const float*)d_in[0];
    const int*   ei = (const int*)d_in[1];   // [2, E] int32
    const float* Wl = (const float*)d_in[2];
    const float* bl = (const float*)d_in[3];
    const float* Wr = (const float*)d_in[4];
    float* out = (float*)d_out;

    // ws layout
    unsigned short* Abf  = (unsigned short*)d_ws;              // N*256 fp16
    unsigned short* Wimg = Abf + (size_t)N_NODES * 256;        // 65536 fp16
    int* cnt   = (int*)(Wimg + 65536);                         // N
    int* slots = cnt + N_NODES;                                // N*CAP
    unsigned int* Xf8 = (unsigned int*)(slots + (size_t)N_NODES * CAP);  // N*32 u32

    hipMemsetAsync(cnt, 0, N_NODES * sizeof(int), stream);

    prep_k<<<SCAT_BLOCKS + PREPX_BLOCKS + WPREP_BLOCKS, 256, 0, stream>>>(
        x, ei, Wl, Wr, (unsigned int*)Abf, Wimg, cnt, slots, Xf8);
    agg_k<<<(N_NODES / 8 * 64 + 255) / 256, 256, 0, stream>>>(
        cnt, slots, Xf8, (unsigned int*)Abf);
    gemm_k<<<GEMM_TILES, 512, 0, stream>>>(Abf, Wimg, bl, out);
}

// Round 16
// 158.834 us; speedup vs baseline: 1.0621x; 1.0339x over previous
//
#include <hip/hip_runtime.h>

// SimpleGraphSAGE: out = mean_agg(x[src]->dst) @ W_l + b_l + x @ W_r
// N=50000, E=640000, IN=128, HID=256.
// R20: revert R19 (BM=224 -> 1 block/CU, nothing hides barrier drains; 3rd
//      gemm regression). Base = exact R16 (best, 155.3us). ONE change:
//      gemm drops the B-LDS staging only. Analysis of R18's failure: A is
//      shared by 4 column-waves (LDS earns it); B is shared only 2x and is
//      a contiguous 1KB read of L2-resident Wimg (128KB) per wave -> LDS
//      round-trip buys nothing. B fragments now load straight from global
//      (bit-identical address algebra, correctness-proven in R18); As +
//      both barriers unchanged. LDS 30->10KB; half the staging ops/kc.

constexpr int N_NODES = 50000;
constexpr int N_EDGES = 640000;
constexpr int GEMM_TILES = (N_NODES + 127) / 128;   // 391
constexpr int CAP = 64;                             // slots per node

constexpr int SCAT_BLOCKS  = N_EDGES / 1024;        // 625, thread handles 4 edges
constexpr int PREPX_BLOCKS = N_NODES * 32 / 256;    // 6250, thread = 4 channels
constexpr int WPREP_BLOCKS = 256;                   // 65536 weight elems

typedef __attribute__((ext_vector_type(8))) short short8;
typedef __attribute__((ext_vector_type(4))) float f32x4;
typedef __attribute__((ext_vector_type(2))) float f32x2;
typedef _Float16 half8 __attribute__((ext_vector_type(8)));

__device__ inline unsigned short f2h(float f) {
    _Float16 h = (_Float16)f;               // v_cvt_f16_f32, RNE
    return __builtin_bit_cast(unsigned short, h);
}

// ---------------------------------------------------------------------------
// prep_k (exact R16): block-range fused [edge scatter | x->fp16+fp8 | W->fp16]
// Abf layout (fp16 [N][256]): ch 0..127 = mean (written by agg), 128..255 = x.
// Xf8: [N][128] fp8 e4m3 image of x, gather source for agg.
// ---------------------------------------------------------------------------
__global__ __launch_bounds__(256) void prep_k(const float* __restrict__ x,
                                              const int* __restrict__ ei,
                                              const float* __restrict__ Wl,
                                              const float* __restrict__ Wr,
                                              unsigned int* __restrict__ Abf_u,
                                              unsigned short* __restrict__ Wimg,
                                              int* __restrict__ cnt,
                                              int* __restrict__ slots,
                                              unsigned int* __restrict__ Xf8_u) {
    int bid = blockIdx.x, tid = threadIdx.x;
    if (bid < SCAT_BLOCKS) {
        int base = bid * 1024 + tid;
#pragma unroll
        for (int k = 0; k < 4; k++) {
            int e   = base + k * 256;
            int src = ei[e];
            int dst = ei[N_EDGES + e];
            int pos = atomicAdd(&cnt[dst], 1);
            if (pos < CAP) slots[(size_t)dst * CAP + pos] = src;
        }
    } else if (bid < SCAT_BLOCKS + PREPX_BLOCKS) {
        int t = (bid - SCAT_BLOCKS) * 256 + tid;          // < N*32
        float4 v = reinterpret_cast<const float4*>(x)[t];
        unsigned int p0 = (unsigned int)f2h(v.x) | ((unsigned int)f2h(v.y) << 16);
        unsigned int p1 = (unsigned int)f2h(v.z) | ((unsigned int)f2h(v.w) << 16);
        int row = t >> 5, c = t & 31;
        reinterpret_cast<uint2*>(Abf_u)[(size_t)row * 64 + 32 + c] =
            make_uint2(p0, p1);
        // fp8 e4m3 image (4 values -> 4 bytes), HW packed convert
        int u8 = __builtin_amdgcn_cvt_pk_fp8_f32(v.x, v.y, 0, false);
        u8     = __builtin_amdgcn_cvt_pk_fp8_f32(v.z, v.w, u8, true);
        Xf8_u[t] = (unsigned int)u8;
    } else {
        int t = (bid - SCAT_BLOCKS - PREPX_BLOCKS) * 256 + tid;  // < 65536
        int k = t >> 8, n = t & 255;
        float v = (k < 128) ? Wl[k * 256 + n] : Wr[(k - 128) * 256 + n];
        Wimg[(size_t)(k >> 5) * 8192 + n * 32 + (k & 31)] = f2h(v);
    }
}

// ---------------------------------------------------------------------------
// agg_k (exact R16): 8 nodes per wave, 8 lanes per node (sub owns 16B =
// 16 fp8 ch of the 128B row). Coalesced slot-batch load + shfl(.,J,8)
// broadcast; 8 gather chains in flight; f32 accumulate; mean -> fp16 Abf.
// ---------------------------------------------------------------------------
__global__ __launch_bounds__(256) void agg_k(const int* __restrict__ cnt,
                                             const int* __restrict__ slots,
                                             const unsigned int* __restrict__ Xf8_u,
                                             unsigned int* __restrict__ Abf_u) {
    int wave = (blockIdx.x * 256 + threadIdx.x) >> 6;  // 0..6251 (guarded)
    int lane = threadIdx.x & 63;
    int g    = lane >> 3;
    int sub  = lane & 7;
    int node = wave * 8 + g;
    if (node >= N_NODES) return;
    int dc   = cnt[node];
    int deg  = (dc > CAP) ? CAP : dc;
    const int* sl = slots + (size_t)node * CAP;
    const uint4* X8 = reinterpret_cast<const uint4*>(Xf8_u);  // row = 8 uint4

    f32x2 a0 = {0.f, 0.f}, a1 = {0.f, 0.f}, a2 = {0.f, 0.f}, a3 = {0.f, 0.f};
    f32x2 a4 = {0.f, 0.f}, a5 = {0.f, 0.f}, a6 = {0.f, 0.f}, a7 = {0.f, 0.f};

#define LOADV(vj, J)                                                    \
    uint4 vj = make_uint4(0, 0, 0, 0);                                  \
    {                                                                   \
        int sj = __shfl(slv, (J), 8);                                   \
        if (base + (J) < deg)                                           \
            vj = X8[(size_t)sj * 8 + sub];                              \
    }
#define ACCV(vj)                                                              \
    {                                                                         \
        a0 += __builtin_amdgcn_cvt_pk_f32_fp8(vj.x, false);                   \
        a1 += __builtin_amdgcn_cvt_pk_f32_fp8(vj.x, true);                    \
        a2 += __builtin_amdgcn_cvt_pk_f32_fp8(vj.y, false);                   \
        a3 += __builtin_amdgcn_cvt_pk_f32_fp8(vj.y, true);                    \
        a4 += __builtin_amdgcn_cvt_pk_f32_fp8(vj.z, false);                   \
        a5 += __builtin_amdgcn_cvt_pk_f32_fp8(vj.z, true);                    \
        a6 += __builtin_amdgcn_cvt_pk_f32_fp8(vj.w, false);                   \
        a7 += __builtin_amdgcn_cvt_pk_f32_fp8(vj.w, true);                    \
    }

    for (int base = 0; base < deg; base += 8) {
        int slv = sl[base + sub];   // 8 lanes cover the batch (32B line)
        LOADV(v0, 0) LOADV(v1, 1) LOADV(v2, 2) LOADV(v3, 3)
        LOADV(v4, 4) LOADV(v5, 5) LOADV(v6, 6) LOADV(v7, 7)
        ACCV(v0) ACCV(v1) ACCV(v2) ACCV(v3)
        ACCV(v4) ACCV(v5) ACCV(v6) ACCV(v7)
    }
#undef LOADV
#undef ACCV

    float inv = (dc > 0) ? 1.0f / (float)dc : 0.0f;
    uint4 o0, o1;
    o0.x = (unsigned int)f2h(a0.x * inv) | ((unsigned int)f2h(a0.y * inv) << 16);
    o0.y = (unsigned int)f2h(a1.x * inv) | ((unsigned int)f2h(a1.y * inv) << 16);
    o0.z = (unsigned int)f2h(a2.x * inv) | ((unsigned int)f2h(a2.y * inv) << 16);
    o0.w = (unsigned int)f2h(a3.x * inv) | ((unsigned int)f2h(a3.y * inv) << 16);
    o1.x = (unsigned int)f2h(a4.x * inv) | ((unsigned int)f2h(a4.y * inv) << 16);
    o1.y = (unsigned int)f2h(a5.x * inv) | ((unsigned int)f2h(a5.y * inv) << 16);
    o1.z = (unsigned int)f2h(a6.x * inv) | ((unsigned int)f2h(a6.y * inv) << 16);
    o1.w = (unsigned int)f2h(a7.x * inv) | ((unsigned int)f2h(a7.y * inv) << 16);
    uint4* A4 = reinterpret_cast<uint4*>(Abf_u);   // row = 32 uint4 (512B)
    A4[(size_t)node * 32 + sub * 2]     = o0;      // ch sub*16 .. sub*16+7
    A4[(size_t)node * 32 + sub * 2 + 1] = o1;      // ch sub*16+8 .. sub*16+15
}

// ---------------------------------------------------------------------------
// gemm_k (R20): out[N][256] = Abf[N][256] @ Wcat[256][256] + bl, fp16 MFMA.
// BM=128, 512 threads = 8 waves (2 row-halves x 4 col-quarters), verified
// R15 structure — but B fragments load DIRECTLY from global (contiguous
// 1KB of L2-resident Wimg per wave; only 2x inter-wave sharing, LDS not
// worth it). A stays LDS-staged (shared by 4 column-waves). LDS 10KB.
// ---------------------------------------------------------------------------
__global__ __launch_bounds__(512) void gemm_k(const unsigned short* __restrict__ Abf,
                                              const unsigned short* __restrict__ Wimg,
                                              const float* __restrict__ bl,
                                              float* __restrict__ out) {
    __shared__ unsigned short As[128 * 40];   // rows padded to 40 elems (80B)

    int tid  = threadIdx.x;
    int w8   = tid >> 6;        // 0..7
    int wm   = w8 >> 2;         // 0..1  row-half
    int wn   = w8 & 3;          // 0..3  col-quarter
    int lane = tid & 63;
    int m15  = lane & 15;
    int quad = lane >> 4;
    int bm   = blockIdx.x * 128;

    f32x4 zero4 = {0.f, 0.f, 0.f, 0.f};
    f32x4 acc[4][4];
#pragma unroll
    for (int rt = 0; rt < 4; rt++)
#pragma unroll
        for (int ct = 0; ct < 4; ct++) acc[rt][ct] = zero4;

    // B frag (ct,kc): Wimg[kc*8192 + (wn*64 + ct*16 + m15)*32 + quad*8]
    const unsigned short* Bbase =
        Wimg + ((size_t)(wn * 64 + m15) * 32 + quad * 8);

    for (int kc = 0; kc < 8; kc++) {
        {   // stage A: 128 rows x 32 halves, one 16B chunk per thread
            int row = tid >> 2, q = tid & 3;
            int grow = bm + row;
            short8 v = {0, 0, 0, 0, 0, 0, 0, 0};
            if (grow < N_NODES)
                v = *reinterpret_cast<const short8*>(
                        Abf + (size_t)grow * 256 + kc * 32 + q * 8);
            *reinterpret_cast<short8*>(As + row * 40 + q * 8) = v;
        }
        __syncthreads();

        half8 Af[4], Bf[4];
#pragma unroll
        for (int ct = 0; ct < 4; ct++)
            Bf[ct] = *reinterpret_cast<const half8*>(
                         Bbase + (size_t)kc * 8192 + ct * 512);
#pragma unroll
        for (int rt = 0; rt < 4; rt++)
            Af[rt] = *reinterpret_cast<const half8*>(
                         As + (wm * 64 + rt * 16 + m15) * 40 + quad * 8);
#pragma unroll
        for (int rt = 0; rt < 4; rt++)
#pragma unroll
            for (int ct = 0; ct < 4; ct++)
                acc[rt][ct] = __builtin_amdgcn_mfma_f32_16x16x32_f16(
                    Af[rt], Bf[ct], acc[rt][ct], 0, 0, 0);
        __syncthreads();
    }

    float bias[4];
#pragma unroll
    for (int ct = 0; ct < 4; ct++) bias[ct] = bl[wn * 64 + ct * 16 + m15];
#pragma unroll
    for (int rt = 0; rt < 4; rt++) {
        int rb = bm + wm * 64 + rt * 16 + quad * 4;
#pragma unroll
        for (int r = 0; r < 4; r++) {
            int row = rb + r;
            if (row < N_NODES) {
#pragma unroll
                for (int ct = 0; ct < 4; ct++)
                    out[(size_t)row * 256 + wn * 64 + ct * 16 + m15] =
                        acc[rt][ct][r] + bias[ct];
            }
        }
    }
}

extern "C" void kernel_launch(void* const* d_in, const int* in_sizes, int n_in,
                              void* d_out, int out_size, void* d_ws, size_t ws_size,
                              hipStream_t stream) {
    const float* x  = (const float*)d_in[0];
    const int*   ei = (const int*)d_in[1];   // [2, E] int32
    const float* Wl = (const float*)d_in[2];
    const float* bl = (const float*)d_in[3];
    const float* Wr = (const float*)d_in[4];
    float* out = (float*)d_out;

    // ws layout
    unsigned short* Abf  = (unsigned short*)d_ws;              // N*256 fp16
    unsigned short* Wimg = Abf + (size_t)N_NODES * 256;        // 65536 fp16
    int* cnt   = (int*)(Wimg + 65536);                         // N
    int* slots = cnt + N_NODES;                                // N*CAP
    unsigned int* Xf8 = (unsigned int*)(slots + (size_t)N_NODES * CAP);  // N*32 u32

    hipMemsetAsync(cnt, 0, N_NODES * sizeof(int), stream);

    prep_k<<<SCAT_BLOCKS + PREPX_BLOCKS + WPREP_BLOCKS, 256, 0, stream>>>(
        x, ei, Wl, Wr, (unsigned int*)Abf, Wimg, cnt, slots, Xf8);
    agg_k<<<(N_NODES / 8 * 64 + 255) / 256, 256, 0, stream>>>(
        cnt, slots, Xf8, (unsigned int*)Abf);
    gemm_k<<<GEMM_TILES, 512, 0, stream>>>(Abf, Wimg, bl, out);
}